// Round 15
// baseline (453.630 us; speedup 1.0000x reference)
//
#include <hip/hip_runtime.h>

typedef __attribute__((ext_vector_type(4))) float f32x4;
typedef __attribute__((ext_vector_type(8))) short short8;
typedef __attribute__((ext_vector_type(4))) short s16x4;
typedef __attribute__((ext_vector_type(4))) unsigned short us4;
typedef unsigned short u16;
typedef unsigned char uchar;

__device__ __forceinline__ u16 f2b(float f) {
  union { float f; unsigned u; } a; a.f = f;
  unsigned r = a.u + 0x7fffu + ((a.u >> 16) & 1u);
  return (u16)(r >> 16);
}
__device__ __forceinline__ unsigned cvtpk2(float lo, float hi) {
  unsigned r;
  asm("v_cvt_pk_bf16_f32 %0, %1, %2" : "=v"(r) : "v"(lo), "v"(hi));
  return r;
}
__device__ __forceinline__ short8 cvt8(f32x4 a, f32x4 b) {
  union { unsigned u[4]; short8 s; } r;
  r.u[0] = cvtpk2(a[0], a[1]); r.u[1] = cvtpk2(a[2], a[3]);
  r.u[2] = cvtpk2(b[0], b[1]); r.u[3] = cvtpk2(b[2], b[3]);
  return r.s;
}
// XOR swizzle for [rows][128B] LDS tiles
#define SWZ(r, byteoff) ((((r) * 128) + (byteoff)) ^ (((r) & 7) << 4))
#define C2 0.18033688011112158f   // 0.125 * log2(e)

typedef __attribute__((address_space(1))) const void* gp1;
typedef __attribute__((address_space(3))) void* lp3;
__device__ __forceinline__ void gload16(const void* g, void* lds_wave_uniform_base) {
  __builtin_amdgcn_global_load_lds((gp1)g, (lp3)lds_wave_uniform_base, 16, 0, 0);
}
// counted-vmcnt raw-barrier helpers (T4)
__device__ __forceinline__ void waitv0() { asm volatile("s_waitcnt vmcnt(0)" ::: "memory"); }
__device__ __forceinline__ void waitv1() { asm volatile("s_waitcnt vmcnt(1)" ::: "memory"); }
__device__ __forceinline__ void waitv2() { asm volatile("s_waitcnt vmcnt(2)" ::: "memory"); }
__device__ __forceinline__ void abar()  { __builtin_amdgcn_s_barrier(); }
__device__ __forceinline__ void sbar()  { __builtin_amdgcn_sched_barrier(0); }

// ============ prep: weight transpose+bf16 (wgs 0..1007) | X f32->bf16 (rest) ============
__global__ __launch_bounds__(256) void prep_kernel(
    const float* w0, const float* w1, const float* w2, const float* w3,
    const float* w4, const float* w5, const float* w6, u16* wt,
    const float* __restrict__ h, const float* __restrict__ tx, u16* __restrict__ xb)
{
  const int bid = blockIdx.x, t = threadIdx.x;
  if (bid < 1008) {
    __shared__ float tile[64][65];
    const float* Ws[7] = {w0, w1, w2, w3, w4, w5, w6};
    int z = bid / 144, rem = bid % 144;
    const float* W = Ws[z];
    u16* out = wt + (size_t)z * 589824;
    const int r0 = (rem / 12) * 64, c0 = (rem % 12) * 64;
#pragma unroll
    for (int i = 0; i < 4; ++i) {
      int idx = i * 256 + t;
      int r = idx >> 4, c = (idx & 15) * 4;
      f32x4 v = *(const f32x4*)(W + (size_t)(r0 + r) * 768 + (c0 + c));
      tile[r][c + 0] = v[0]; tile[r][c + 1] = v[1];
      tile[r][c + 2] = v[2]; tile[r][c + 3] = v[3];
    }
    __syncthreads();
#pragma unroll
    for (int i = 0; i < 4; ++i) {
      int idx = i * 256 + t;
      int rn = idx >> 4, c = (idx & 15) * 4;
      union { us4 o; unsigned u[2]; } o;
      o.u[0] = cvtpk2(tile[c + 0][rn], tile[c + 1][rn]);
      o.u[1] = cvtpk2(tile[c + 2][rn], tile[c + 3][rn]);
      *(us4*)(out + (size_t)(c0 + rn) * 768 + (r0 + c)) = o.o;
    }
  } else {
    size_t e = ((size_t)(bid - 1008) * 256 + t) * 8;
    const float* src; size_t off;
    if (e < 6291456) { src = h; off = e; } else { src = tx; off = e - 6291456; }
    f32x4 v0 = *(const f32x4*)(src + off), v1 = *(const f32x4*)(src + off + 4);
    *(short8*)(xb + e) = cvt8(v0, v1);
  }
}

// ============ merged QKV projection (img ids 0..1151, text 1152..1727) ============
__global__ __launch_bounds__(256) void proj_kernel(
    const u16* __restrict__ Xb, const u16* __restrict__ wt,
    const float* __restrict__ bq, const float* __restrict__ bk, const float* __restrict__ bv,
    const float* __restrict__ bqt, const float* __restrict__ bkt, const float* __restrict__ bvt,
    u16* __restrict__ qi, u16* __restrict__ ki, u16* __restrict__ vti,
    u16* __restrict__ qt, u16* __restrict__ ktx, u16* __restrict__ vtt)
{
  const int bid = blockIdx.x;
  const int wk = (bid & 7) * 216 + (bid >> 3);     // bijective, 1728%8==0
  const bool img = wk < 1152;
  const int id = img ? wk : wk - 1152;
  const int y = img ? (id >> 6) : (id >> 5);       // 0..17: same-y blocks share weights
  const int x = img ? (id & 63) : (id & 31);
  const int z = y / 6, n0 = (y % 6) * 128, m0 = x * 128;
  const int S = img ? 1024 : 512, logS = img ? 10 : 9;
  const u16* X = img ? Xb : Xb + 6291456;
  const u16* Wt = wt + (img ? 0 : (size_t)3 * 589824) + (size_t)y * 98304;
  const float* bias = img ? (z == 0 ? bq : z == 1 ? bk : bv)
                          : (z == 0 ? bqt : z == 1 ? bkt : bvt);
  u16* out = img ? (z == 0 ? qi : z == 1 ? ki : vti)
                 : (z == 0 ? qt : z == 1 ? ktx : vtt);
  const bool vmode = (z == 2);
  __shared__ unsigned char sm[36864];
  unsigned char* Asm = sm;
  unsigned char* Bsm = sm + 16384;
  const int t = threadIdx.x, w = t >> 6, l = t & 63;
  const int wm = (w & 1) * 64, wn = (w >> 1) * 64;
  f32x4 acc[4][4] = {};
  for (int k0 = 0; k0 < 768; k0 += 64) {
#pragma unroll
    for (int j = 0; j < 4; ++j) {
      int chunk = j * 4 + w;
      int r = chunk * 8 + (l >> 3);
      int cb = ((l & 7) * 16) ^ ((r & 7) << 4);
      gload16(X + (size_t)(m0 + r) * 768 + k0 + cb / 2, Asm + chunk * 1024);
    }
#pragma unroll
    for (int j = 0; j < 4; ++j) {
      int chunk = j * 4 + w;
      int r = chunk * 8 + (l >> 3);
      int cb = ((l & 7) * 16) ^ ((r & 7) << 4);
      gload16(Wt + (size_t)r * 768 + k0 + cb / 2, Bsm + chunk * 1024);
    }
    __syncthreads();
#pragma unroll
    for (int kc = 0; kc < 2; ++kc) {
      short8 af[4], bfr[4];
      const int koff = (kc * 32 + (l >> 4) * 8) * 2;
#pragma unroll
      for (int ms = 0; ms < 4; ++ms) {
        int row = wm + ms * 16 + (l & 15);
        af[ms] = *(const short8*)(Asm + SWZ(row, koff));
      }
#pragma unroll
      for (int ns = 0; ns < 4; ++ns) {
        int row = wn + ns * 16 + (l & 15);
        bfr[ns] = *(const short8*)(Bsm + SWZ(row, koff));
      }
      __builtin_amdgcn_s_setprio(1);
#pragma unroll
      for (int ms = 0; ms < 4; ++ms)
#pragma unroll
        for (int ns = 0; ns < 4; ++ns)
          acc[ms][ns] = __builtin_amdgcn_mfma_f32_16x16x32_bf16(af[ms], bfr[ns], acc[ms][ns], 0, 0, 0);
      __builtin_amdgcn_s_setprio(0);
    }
    __syncthreads();
  }
  float bvv[4];
#pragma unroll
  for (int ns = 0; ns < 4; ++ns) bvv[ns] = bias[n0 + wn + ns * 16 + (l & 15)];
#pragma unroll
  for (int ms = 0; ms < 4; ++ms)
#pragma unroll
    for (int ns = 0; ns < 4; ++ns)
#pragma unroll
      for (int i = 0; i < 4; ++i) {
        u16 u = f2b(acc[ms][ns][i] + bvv[ns]);
        int mm = wm + ms * 16 + (l >> 4) * 4 + i;
        int nn = wn + ns * 16 + (l & 15);
        int row = vmode ? nn : mm, col = vmode ? mm : nn;
        *(u16*)(sm + row * 272 + col * 2) = u;
      }
  __syncthreads();
  if (!vmode) {
#pragma unroll
    for (int i = 0; i < 8; ++i) {
      int idx = i * 256 + t;
      int r = idx >> 4, c = (idx & 15) * 8;
      short8 v = *(const short8*)(sm + r * 272 + c * 2);
      int sg = m0 + r, b = sg >> logS, s = sg & (S - 1);
      int n = n0 + c, hh = n >> 6, d = n & 63;
      *(short8*)(out + (((size_t)b * 12 + hh) * S + s) * 64 + d) = v;
    }
  } else {
#pragma unroll
    for (int i = 0; i < 8; ++i) {
      int idx = i * 256 + t;
      int r = idx >> 4, c = (idx & 15) * 8;
      short8 v = *(const short8*)(sm + r * 272 + c * 2);
      int n = n0 + r, hh = n >> 6, d = n & 63;
      int sg = m0 + c, b = sg >> logS, s = sg & (S - 1);
      *(short8*)(out + (((size_t)b * 12 + hh) * 64 + d) * S + s) = v;
    }
  }
}

// ============ attention helpers (8 waves/wg, 16 q-rows per wave, M=128, low-VGPR) ============
__device__ __forceinline__ void stage_k8(const u16* Kp, int kt, uchar* Ksm, int w, int l) {
  int r = w * 8 + (l >> 3);
  int cb = ((l & 7) * 16) ^ ((r & 7) << 4);
  gload16(Kp + (size_t)(kt * 64 + r) * 64 + cb / 2, Ksm + w * 1024);
}
__device__ __forceinline__ void stage_v8(const u16* Vp, int kt, int Sk, uchar* Vsm, int w, int l) {
  int r = w * 8 + (l >> 3);
  int cb = ((l & 7) * 16) ^ ((r & 7) << 4);
  gload16(Vp + (size_t)r * Sk + kt * 64 + cb / 2, Vsm + w * 1024);
}
// swapped QK^T, low-reg: two batches of 4 K-fragments (peak kf = 8 VGPR)
__device__ __forceinline__ void qk_swapped(const short8 qf[2], const uchar* Ksm, int l, f32x4 sfr[4]) {
#pragma unroll
  for (int kc = 0; kc < 2; ++kc) {
    short8 kf[4];
#pragma unroll
    for (int sub = 0; sub < 4; ++sub) {
      int row = sub * 16 + (l & 15);
      kf[sub] = *(const short8*)(Ksm + SWZ(row, (kc * 32 + (l >> 4) * 8) * 2));
    }
    __builtin_amdgcn_s_setprio(1);
#pragma unroll
    for (int sub = 0; sub < 4; ++sub)
      sfr[sub] = __builtin_amdgcn_mfma_f32_16x16x32_bf16(kf[sub], qf[kc], sfr[sub], 0, 0, 0);
    __builtin_amdgcn_s_setprio(0);
  }
}
// pack P (sfr[sub][i] post-exp, k=16sub+4hi+i) into sigma-ordered x32 A-frags
__device__ __forceinline__ void pa_sigma(const f32x4 sfr[4], short8 pa[2]) {
#pragma unroll
  for (int kc = 0; kc < 2; ++kc) {
    union { unsigned u[4]; short8 s; } r;
    r.u[0] = cvtpk2(sfr[2 * kc][0], sfr[2 * kc][1]);
    r.u[1] = cvtpk2(sfr[2 * kc][2], sfr[2 * kc][3]);
    r.u[2] = cvtpk2(sfr[2 * kc + 1][0], sfr[2 * kc + 1][1]);
    r.u[3] = cvtpk2(sfr[2 * kc + 1][2], sfr[2 * kc + 1][3]);
    pa[kc] = r.s;
  }
}
// PV with inline V-fragment reads (sigma k-order), 4 live V VGPRs
__device__ __forceinline__ void pv_sigma(const short8 pa[2], const uchar* Vsm, int l, f32x4 og[4]) {
#pragma unroll
  for (int kc = 0; kc < 2; ++kc)
#pragma unroll
    for (int ds = 0; ds < 4; ++ds) {
      int row = ds * 16 + (l & 15);
      union { s16x4 h[2]; short8 s; } u;
      u.h[0] = *(const s16x4*)(Vsm + SWZ(row, 64 * kc + 8 * (l >> 4)));
      u.h[1] = *(const s16x4*)(Vsm + SWZ(row, 64 * kc + 32 + 8 * (l >> 4)));
      __builtin_amdgcn_s_setprio(1);
      og[ds] = __builtin_amdgcn_mfma_f32_16x16x32_bf16(pa[kc], u.s, og[ds], 0, 0, 0);
      __builtin_amdgcn_s_setprio(0);
    }
}
// single dbuf sweep, counted-vmcnt barriers: og += exp2(S*C2)@V; ll = per-lane row-sum (q=l&15)
__device__ __forceinline__ void pass_unnorm(
    const u16* __restrict__ Kp, const u16* __restrict__ Vp, int Sk,
    const short8 qf[2], uchar* Ks0, uchar* Ks1, uchar* Vs0, uchar* Vs1,
    int w, int l, f32x4 og[4], float& ll)
{
  const int nkt = Sk >> 6;
  stage_k8(Kp, 0, Ks0, w, l);
  stage_v8(Vp, 0, Sk, Vs0, w, l);
  for (int kt = 0; kt < nkt; ++kt) {
    uchar* Kc = (kt & 1) ? Ks1 : Ks0;
    uchar* Vc = (kt & 1) ? Vs1 : Vs0;
    if (kt + 1 < nkt) {
      stage_k8(Kp, kt + 1, (kt & 1) ? Ks0 : Ks1, w, l);
      stage_v8(Vp, kt + 1, Sk, (kt & 1) ? Vs0 : Vs1, w, l);
      waitv2();                       // my stage(kt) landed; stage(kt+1) stays in flight
    } else {
      waitv0();
    }
    abar(); sbar();                   // all waves' stage(kt) visible
    f32x4 sfr[4] = {};
    qk_swapped(qf, Kc, l, sfr);
#pragma unroll
    for (int sub = 0; sub < 4; ++sub)
#pragma unroll
      for (int i = 0; i < 4; ++i) {
        float p = exp2f(sfr[sub][i] * C2);
        ll += p;
        sfr[sub][i] = p;              // exp in place (no ps[] array)
      }
    short8 pa[2];
    pa_sigma(sfr, pa);
    pv_sigma(pa, Vc, l, og);
    sbar(); abar();                   // buffer reads done before next overwrite
  }
}

// ============ merged dual-source attention, 512 thr, XCD-class mapping ============
__global__ __launch_bounds__(512, 6) void attn_kernel(
    const u16* __restrict__ qi, const u16* __restrict__ ki, const u16* __restrict__ vti,
    const u16* __restrict__ qt, const u16* __restrict__ ktx, const u16* __restrict__ vtt,
    u16* __restrict__ cimg, u16* __restrict__ ctxt, float* __restrict__ weights)
{
  __shared__ uchar smem[32768];
  const int t = threadIdx.x, w = t >> 6, l = t & 63;
  uchar* Ks0 = smem;
  uchar* Ks1 = smem + 8192;
  uchar* Vs0 = smem + 16384;
  uchar* Vs1 = smem + 24576;

  const int bid = blockIdx.x;
  const int xcd = bid & 7, j = bid >> 3;           // j in 0..143
  const bool img = (j < 96);                       // heavy items first per class (LPT)
  const int id = img ? (xcd * 96 + j)              // img ids 0..767
                     : (xcd * 48 + (j - 96));      // text ids 0..383
  const int x = img ? (id & 7) : (id & 3);
  const int head = img ? (id >> 3) : (id >> 2);    // b*12+h; same-head wgs contiguous per class
  const int b = head / 12, h = head % 12;
  const int Sq = img ? 1024 : 512;
  const int SkA = img ? 1024 : 512, SkB = img ? 512 : 1024;
  const u16* Qp = (img ? qi : qt) + (size_t)head * Sq * 64;
  const u16* KpA = (img ? ki : ktx) + (size_t)head * SkA * 64;
  const u16* VpA = (img ? vti : vtt) + (size_t)head * 64 * SkA;
  const u16* KpB = (img ? ktx : ki) + (size_t)head * SkB * 64;
  const u16* VpB = (img ? vtt : vti) + (size_t)head * 64 * SkB;
  u16* CTX = img ? cimg : ctxt;
  float* PROBS = img ? weights : nullptr;
  const int q0 = x * 128;
  const int qrow = q0 + w * 16 + (l & 15);         // this lane's q row (within head)

  short8 qf[2];
  qf[0] = *(const short8*)(Qp + (size_t)qrow * 64 + (l >> 4) * 8);
  qf[1] = *(const short8*)(Qp + (size_t)qrow * 64 + 32 + (l >> 4) * 8);

  f32x4 of[4] = {};
  if (PROBS) {
    // ---- pass 1 over A: denominators only (K dbuf, counted vmcnt) ----
    float ll = 0.f;
    const int nkt = SkA >> 6;
    stage_k8(KpA, 0, Ks0, w, l);
    for (int kt = 0; kt < nkt; ++kt) {
      uchar* Kc = (kt & 1) ? Ks1 : Ks0;
      if (kt + 1 < nkt) {
        stage_k8(KpA, kt + 1, (kt & 1) ? Ks0 : Ks1, w, l);
        waitv1();
      } else {
        waitv0();
      }
      abar(); sbar();
      f32x4 sfr[4] = {};
      qk_swapped(qf, Kc, l, sfr);
#pragma unroll
      for (int sub = 0; sub < 4; ++sub)
#pragma unroll
        for (int i = 0; i < 4; ++i) ll += exp2f(sfr[sub][i] * C2);
      sbar(); abar();
    }
    // pass-2 prologue staged early; reduce hides part of the latency
    stage_k8(KpA, 0, Ks0, w, l);
    stage_v8(VpA, 0, SkA, Vs0, w, l);
    ll += __shfl_xor(ll, 16);
    ll += __shfl_xor(ll, 32);
    const float lb = -__log2f(ll);                 // p_norm = exp2(S*C2 + lb)
    // ---- pass 2 over A: normalized probs direct-out + PV (K,V dbuf, counted vmcnt) ----
    float* prow = PROBS + ((size_t)head * Sq + qrow) * SkA;
    for (int kt = 0; kt < nkt; ++kt) {
      uchar* Kc = (kt & 1) ? Ks1 : Ks0;
      uchar* Vc = (kt & 1) ? Vs1 : Vs0;
      if (kt + 1 < nkt) {
        stage_k8(KpA, kt + 1, (kt & 1) ? Ks0 : Ks1, w, l);
        stage_v8(VpA, kt + 1, SkA, (kt & 1) ? Vs0 : Vs1, w, l);
        waitv2();
      } else {
        waitv0();
      }
      abar(); sbar();
      f32x4 sfr[4] = {};
      qk_swapped(qf, Kc, l, sfr);
#pragma unroll
      for (int sub = 0; sub < 4; ++sub) {
#pragma unroll
        for (int i = 0; i < 4; ++i)
          sfr[sub][i] = exp2f(sfr[sub][i] * C2 + lb);
        // direct probs store: row q=l&15, k = 16sub+4hi .. +3 (16B aligned)
        *(f32x4*)(prow + kt * 64 + sub * 16 + (l >> 4) * 4) = sfr[sub];
      }
      short8 pa[2];
      pa_sigma(sfr, pa);
      pv_sigma(pa, Vc, l, of);
      sbar(); abar();
    }
#pragma unroll
    for (int ds = 0; ds < 4; ++ds) of[ds] *= 0.5f;
  } else {
    float ll = 0.f;
    pass_unnorm(KpA, VpA, SkA, qf, Ks0, Ks1, Vs0, Vs1, w, l, of, ll);
    ll += __shfl_xor(ll, 16);
    ll += __shfl_xor(ll, 32);
    float r = 0.5f / ll;
#pragma unroll
    for (int i = 0; i < 4; ++i) {
      float lv = __int_as_float(__builtin_amdgcn_ds_bpermute(
          ((l >> 4) * 4 + i) * 4, __float_as_int(r)));
#pragma unroll
      for (int ds = 0; ds < 4; ++ds) of[ds][i] *= lv;
    }
  }
  // ---- source B: single unnormalized dbuf sweep ----
  {
    f32x4 og[4] = {};
    float l2 = 0.f;
    pass_unnorm(KpB, VpB, SkB, qf, Ks0, Ks1, Vs0, Vs1, w, l, og, l2);
    l2 += __shfl_xor(l2, 16);
    l2 += __shfl_xor(l2, 32);
    float r = 0.5f / l2;
#pragma unroll
    for (int i = 0; i < 4; ++i) {
      float lv = __int_as_float(__builtin_amdgcn_ds_bpermute(
          ((l >> 4) * 4 + i) * 4, __float_as_int(r)));
#pragma unroll
      for (int ds = 0; ds < 4; ++ds) of[ds][i] += og[ds][i] * lv;
    }
  }
  // ---- write merged ctx via per-wave LDS bounce (K/V buffers dead after barrier) ----
  __syncthreads();
  {
    uchar* Wb = smem + w * 2176;                   // 16 rows x 68 u16 (136B stride)
#pragma unroll
    for (int ds = 0; ds < 4; ++ds)
#pragma unroll
      for (int i = 0; i < 4; ++i)
        *(u16*)(Wb + ((l >> 4) * 4 + i) * 136 + (16 * ds + (l & 15)) * 2) = f2b(of[ds][i]);
#pragma unroll
    for (int i = 0; i < 2; ++i) {
      int it = i * 64 + l;
      int r = it >> 3, cg = it & 7;
      short8 v = *(const short8*)(Wb + r * 136 + cg * 16);
      int s = q0 + w * 16 + r;
      *(short8*)(CTX + ((size_t)b * Sq + s) * 768 + h * 64 + cg * 8) = v;
    }
  }
}

// ============ merged output projection (img ids 0..383, text 384..575) ============
__global__ __launch_bounds__(256) void outproj_kernel(
    const u16* __restrict__ cimg, const u16* __restrict__ ctxt,
    const u16* __restrict__ Wto, const float* __restrict__ bias,
    float* __restrict__ out_img, float* __restrict__ out_text)
{
  const int bid = blockIdx.x;
  const int wk = (bid & 7) * 72 + (bid >> 3);      // bijective, 576%8==0
  const bool img = wk < 384;
  const int id = img ? wk : wk - 384;
  const int y = img ? (id >> 6) : (id >> 5);       // same-y blocks share Wo panel
  const int x = img ? (id & 63) : (id & 31);
  const u16* C = img ? cimg : ctxt;
  float* OUT = img ? out_img : out_text;
  const int m0 = x * 128, n0 = y * 128;
  __shared__ unsigned char sm[32768];
  unsigned char* Asm = sm;
  unsigned char* Bsm = sm + 16384;
  const int t = threadIdx.x, w = t >> 6, l = t & 63;
  const int wm = (w & 1) * 64, wn = (w >> 1) * 64;
  f32x4 acc[4][4] = {};
  for (int k0 = 0; k0 < 768; k0 += 64) {
#pragma unroll
    for (int j = 0; j < 4; ++j) {
      int chunk = j * 4 + w;
      int r = chunk * 8 + (l >> 3);
      int cb = ((l & 7) * 16) ^ ((r & 7) << 4);
      gload16(C + (size_t)(m0 + r) * 768 + k0 + cb / 2, Asm + chunk * 1024);
    }
#pragma unroll
    for (int j = 0; j < 4; ++j) {
      int chunk = j * 4 + w;
      int r = chunk * 8 + (l >> 3);
      int cb = ((l & 7) * 16) ^ ((r & 7) << 4);
      gload16(Wto + (size_t)(n0 + r) * 768 + k0 + cb / 2, Bsm + chunk * 1024);
    }
    __syncthreads();
#pragma unroll
    for (int kc = 0; kc < 2; ++kc) {
      short8 af[4], bfr[4];
      const int koff = (kc * 32 + (l >> 4) * 8) * 2;
#pragma unroll
      for (int ms = 0; ms < 4; ++ms) {
        int row = wm + ms * 16 + (l & 15);
        af[ms] = *(const short8*)(Asm + SWZ(row, koff));
      }
#pragma unroll
      for (int ns = 0; ns < 4; ++ns) {
        int row = wn + ns * 16 + (l & 15);
        bfr[ns] = *(const short8*)(Bsm + SWZ(row, koff));
      }
      __builtin_amdgcn_s_setprio(1);
#pragma unroll
      for (int ms = 0; ms < 4; ++ms)
#pragma unroll
        for (int ns = 0; ns < 4; ++ns)
          acc[ms][ns] = __builtin_amdgcn_mfma_f32_16x16x32_bf16(af[ms], bfr[ns], acc[ms][ns], 0, 0, 0);
      __builtin_amdgcn_s_setprio(0);
    }
    __syncthreads();
  }
#pragma unroll
  for (int ms = 0; ms < 4; ++ms)
#pragma unroll
    for (int ns = 0; ns < 4; ++ns) {
      float bv = bias[n0 + wn + ns * 16 + (l & 15)];
#pragma unroll
      for (int i = 0; i < 4; ++i) {
        int mm = m0 + wm + ms * 16 + (l >> 4) * 4 + i;
        int nn = n0 + wn + ns * 16 + (l & 15);
        OUT[(size_t)mm * 768 + nn] = acc[ms][ns][i] + bv;
      }
    }
}

extern "C" void kernel_launch(void* const* d_in, const int* in_sizes, int n_in,
                              void* d_out, int out_size, void* d_ws, size_t ws_size,
                              hipStream_t stream)
{
  const float* hidden = (const float*)d_in[0];
  const float* text   = (const float*)d_in[1];
  const float* Wq  = (const float*)d_in[2];  const float* bq  = (const float*)d_in[3];
  const float* Wk  = (const float*)d_in[4];  const float* bk  = (const float*)d_in[5];
  const float* Wv  = (const float*)d_in[6];  const float* bv  = (const float*)d_in[7];
  const float* Wqt = (const float*)d_in[8];  const float* bqt = (const float*)d_in[9];
  const float* Wkt = (const float*)d_in[10]; const float* bkt = (const float*)d_in[11];
  const float* Wvt = (const float*)d_in[12]; const float* bvt = (const float*)d_in[13];
  const float* Wo  = (const float*)d_in[14]; const float* bo  = (const float*)d_in[15];

  u16* wt   = (u16*)d_ws;                 // 7 * 589824
  u16* xb   = wt + 7 * 589824;            // hidden bf16 (6291456) + text bf16 (3145728)
  u16* qi   = xb + 9437184;               // [8][12][1024][64]
  u16* ki   = qi + 6291456;
  u16* vti  = ki + 6291456;               // [8][12][64][1024]
  u16* qt   = vti + 6291456;              // [8][12][512][64]
  u16* ktx  = qt + 3145728;
  u16* vtt  = ktx + 3145728;              // [8][12][64][512]
  u16* cimg = vtt + 3145728;              // [8][1024][768] = 0.5*(ctx_ii+ctx_it)
  u16* ctxt = cimg + 6291456;             // [8][512][768]  = 0.5*(ctx_tt+ctx_ti)

  float* out_img  = (float*)d_out;
  float* out_text = out_img + 6291456;
  float* weights  = out_text + 3145728;

  prep_kernel<<<5616, 256, 0, stream>>>(Wq, Wk, Wv, Wqt, Wkt, Wvt, Wo, wt,
                                        hidden, text, xb);
  proj_kernel<<<1728, 256, 0, stream>>>(xb, wt, bq, bk, bv, bqt, bkt, bvt,
                                        qi, ki, vti, qt, ktx, vtt);
  attn_kernel<<<1152, 512, 0, stream>>>(qi, ki, vti, qt, ktx, vtt,
                                        cimg, ctxt, weights);
  outproj_kernel<<<576, 256, 0, stream>>>(cimg, ctxt, wt + 6 * 589824, bo,
                                          out_img, out_text);
}

// Round 16
// 311.819 us; speedup vs baseline: 1.4548x; 1.4548x over previous
//
#include <hip/hip_runtime.h>

typedef __attribute__((ext_vector_type(4))) float f32x4;
typedef __attribute__((ext_vector_type(8))) short short8;
typedef __attribute__((ext_vector_type(4))) short s16x4;
typedef __attribute__((ext_vector_type(4))) unsigned short us4;
typedef unsigned short u16;
typedef unsigned char uchar;

__device__ __forceinline__ u16 f2b(float f) {
  union { float f; unsigned u; } a; a.f = f;
  unsigned r = a.u + 0x7fffu + ((a.u >> 16) & 1u);
  return (u16)(r >> 16);
}
__device__ __forceinline__ unsigned cvtpk2(float lo, float hi) {
  unsigned r;
  asm("v_cvt_pk_bf16_f32 %0, %1, %2" : "=v"(r) : "v"(lo), "v"(hi));
  return r;
}
__device__ __forceinline__ short8 cvt8(f32x4 a, f32x4 b) {
  union { unsigned u[4]; short8 s; } r;
  r.u[0] = cvtpk2(a[0], a[1]); r.u[1] = cvtpk2(a[2], a[3]);
  r.u[2] = cvtpk2(b[0], b[1]); r.u[3] = cvtpk2(b[2], b[3]);
  return r.s;
}
// XOR swizzle for [rows][128B] LDS tiles
#define SWZ(r, byteoff) ((((r) * 128) + (byteoff)) ^ (((r) & 7) << 4))
#define C2 0.18033688011112158f   // 0.125 * log2(e)

typedef __attribute__((address_space(1))) const void* gp1;
typedef __attribute__((address_space(3))) void* lp3;
__device__ __forceinline__ void gload16(const void* g, void* lds_wave_uniform_base) {
  __builtin_amdgcn_global_load_lds((gp1)g, (lp3)lds_wave_uniform_base, 16, 0, 0);
}
// counted-vmcnt raw-barrier helpers (T4)
__device__ __forceinline__ void waitv0() { asm volatile("s_waitcnt vmcnt(0)" ::: "memory"); }
__device__ __forceinline__ void waitv1() { asm volatile("s_waitcnt vmcnt(1)" ::: "memory"); }
__device__ __forceinline__ void waitv2() { asm volatile("s_waitcnt vmcnt(2)" ::: "memory"); }
__device__ __forceinline__ void abar()  { __builtin_amdgcn_s_barrier(); }
__device__ __forceinline__ void sbar()  { __builtin_amdgcn_sched_barrier(0); }

// ============ prep: weight transpose+bf16 (wgs 0..1007) | X f32->bf16 (rest) ============
__global__ __launch_bounds__(256) void prep_kernel(
    const float* w0, const float* w1, const float* w2, const float* w3,
    const float* w4, const float* w5, const float* w6, u16* wt,
    const float* __restrict__ h, const float* __restrict__ tx, u16* __restrict__ xb)
{
  const int bid = blockIdx.x, t = threadIdx.x;
  if (bid < 1008) {
    __shared__ float tile[64][65];
    const float* Ws[7] = {w0, w1, w2, w3, w4, w5, w6};
    int z = bid / 144, rem = bid % 144;
    const float* W = Ws[z];
    u16* out = wt + (size_t)z * 589824;
    const int r0 = (rem / 12) * 64, c0 = (rem % 12) * 64;
#pragma unroll
    for (int i = 0; i < 4; ++i) {
      int idx = i * 256 + t;
      int r = idx >> 4, c = (idx & 15) * 4;
      f32x4 v = *(const f32x4*)(W + (size_t)(r0 + r) * 768 + (c0 + c));
      tile[r][c + 0] = v[0]; tile[r][c + 1] = v[1];
      tile[r][c + 2] = v[2]; tile[r][c + 3] = v[3];
    }
    __syncthreads();
#pragma unroll
    for (int i = 0; i < 4; ++i) {
      int idx = i * 256 + t;
      int rn = idx >> 4, c = (idx & 15) * 4;
      union { us4 o; unsigned u[2]; } o;
      o.u[0] = cvtpk2(tile[c + 0][rn], tile[c + 1][rn]);
      o.u[1] = cvtpk2(tile[c + 2][rn], tile[c + 3][rn]);
      *(us4*)(out + (size_t)(c0 + rn) * 768 + (r0 + c)) = o.o;
    }
  } else {
    size_t e = ((size_t)(bid - 1008) * 256 + t) * 8;
    const float* src; size_t off;
    if (e < 6291456) { src = h; off = e; } else { src = tx; off = e - 6291456; }
    f32x4 v0 = *(const f32x4*)(src + off), v1 = *(const f32x4*)(src + off + 4);
    *(short8*)(xb + e) = cvt8(v0, v1);
  }
}

// ============ merged QKV projection, L2-supergrouped mapping ============
// img ids 0..1151: supergroups of 72 = 4 x-tiles x 18 y (X rows + all QKV panels ~4.3MB L2-fit)
// text ids 0..575 (after img): same structure, 8 supergroups.
__global__ __launch_bounds__(256) void proj_kernel(
    const u16* __restrict__ Xb, const u16* __restrict__ wt,
    const float* __restrict__ bq, const float* __restrict__ bk, const float* __restrict__ bv,
    const float* __restrict__ bqt, const float* __restrict__ bkt, const float* __restrict__ bvt,
    u16* __restrict__ qi, u16* __restrict__ ki, u16* __restrict__ vti,
    u16* __restrict__ qt, u16* __restrict__ ktx, u16* __restrict__ vtt)
{
  const int bid = blockIdx.x;
  const int wk = (bid & 7) * 216 + (bid >> 3);     // bijective, 1728%8==0
  const bool img = wk < 1152;
  const int id = img ? wk : wk - 1152;
  const int sg = id / 72, r72 = id % 72;           // supergroup of 72 wgs
  const int y = r72 >> 2;                          // 0..17 (weight panel)
  const int x = sg * 4 + (r72 & 3);                // m-tile
  const int z = y / 6, n0 = (y % 6) * 128, m0 = x * 128;
  const int S = img ? 1024 : 512, logS = img ? 10 : 9;
  const u16* X = img ? Xb : Xb + 6291456;
  const u16* Wt = wt + (img ? 0 : (size_t)3 * 589824) + (size_t)y * 98304;
  const float* bias = img ? (z == 0 ? bq : z == 1 ? bk : bv)
                          : (z == 0 ? bqt : z == 1 ? bkt : bvt);
  u16* out = img ? (z == 0 ? qi : z == 1 ? ki : vti)
                 : (z == 0 ? qt : z == 1 ? ktx : vtt);
  const bool vmode = (z == 2);
  __shared__ unsigned char sm[36864];
  unsigned char* Asm = sm;
  unsigned char* Bsm = sm + 16384;
  const int t = threadIdx.x, w = t >> 6, l = t & 63;
  const int wm = (w & 1) * 64, wn = (w >> 1) * 64;
  f32x4 acc[4][4] = {};
  for (int k0 = 0; k0 < 768; k0 += 64) {
#pragma unroll
    for (int j = 0; j < 4; ++j) {
      int chunk = j * 4 + w;
      int r = chunk * 8 + (l >> 3);
      int cb = ((l & 7) * 16) ^ ((r & 7) << 4);
      gload16(X + (size_t)(m0 + r) * 768 + k0 + cb / 2, Asm + chunk * 1024);
    }
#pragma unroll
    for (int j = 0; j < 4; ++j) {
      int chunk = j * 4 + w;
      int r = chunk * 8 + (l >> 3);
      int cb = ((l & 7) * 16) ^ ((r & 7) << 4);
      gload16(Wt + (size_t)r * 768 + k0 + cb / 2, Bsm + chunk * 1024);
    }
    __syncthreads();
#pragma unroll
    for (int kc = 0; kc < 2; ++kc) {
      short8 af[4], bfr[4];
      const int koff = (kc * 32 + (l >> 4) * 8) * 2;
#pragma unroll
      for (int ms = 0; ms < 4; ++ms) {
        int row = wm + ms * 16 + (l & 15);
        af[ms] = *(const short8*)(Asm + SWZ(row, koff));
      }
#pragma unroll
      for (int ns = 0; ns < 4; ++ns) {
        int row = wn + ns * 16 + (l & 15);
        bfr[ns] = *(const short8*)(Bsm + SWZ(row, koff));
      }
      __builtin_amdgcn_s_setprio(1);
#pragma unroll
      for (int ms = 0; ms < 4; ++ms)
#pragma unroll
        for (int ns = 0; ns < 4; ++ns)
          acc[ms][ns] = __builtin_amdgcn_mfma_f32_16x16x32_bf16(af[ms], bfr[ns], acc[ms][ns], 0, 0, 0);
      __builtin_amdgcn_s_setprio(0);
    }
    __syncthreads();
  }
  float bvv[4];
#pragma unroll
  for (int ns = 0; ns < 4; ++ns) bvv[ns] = bias[n0 + wn + ns * 16 + (l & 15)];
#pragma unroll
  for (int ms = 0; ms < 4; ++ms)
#pragma unroll
    for (int ns = 0; ns < 4; ++ns)
#pragma unroll
      for (int i = 0; i < 4; ++i) {
        u16 u = f2b(acc[ms][ns][i] + bvv[ns]);
        int mm = wm + ms * 16 + (l >> 4) * 4 + i;
        int nn = wn + ns * 16 + (l & 15);
        int row = vmode ? nn : mm, col = vmode ? mm : nn;
        *(u16*)(sm + row * 272 + col * 2) = u;
      }
  __syncthreads();
  if (!vmode) {
#pragma unroll
    for (int i = 0; i < 8; ++i) {
      int idx = i * 256 + t;
      int r = idx >> 4, c = (idx & 15) * 8;
      short8 v = *(const short8*)(sm + r * 272 + c * 2);
      int sg2 = m0 + r, b = sg2 >> logS, s = sg2 & (S - 1);
      int n = n0 + c, hh = n >> 6, d = n & 63;
      *(short8*)(out + (((size_t)b * 12 + hh) * S + s) * 64 + d) = v;
    }
  } else {
#pragma unroll
    for (int i = 0; i < 8; ++i) {
      int idx = i * 256 + t;
      int r = idx >> 4, c = (idx & 15) * 8;
      short8 v = *(const short8*)(sm + r * 272 + c * 2);
      int n = n0 + r, hh = n >> 6, d = n & 63;
      int sg2 = m0 + c, b = sg2 >> logS, s = sg2 & (S - 1);
      *(short8*)(out + (((size_t)b * 12 + hh) * 64 + d) * S + s) = v;
    }
  }
}

// ============ attention helpers (8 waves/wg, 16 q-rows per wave, M=128) ============
__device__ __forceinline__ void stage_k8(const u16* Kp, int kt, uchar* Ksm, int w, int l) {
  int r = w * 8 + (l >> 3);
  int cb = ((l & 7) * 16) ^ ((r & 7) << 4);
  gload16(Kp + (size_t)(kt * 64 + r) * 64 + cb / 2, Ksm + w * 1024);
}
__device__ __forceinline__ void stage_v8(const u16* Vp, int kt, int Sk, uchar* Vsm, int w, int l) {
  int r = w * 8 + (l >> 3);
  int cb = ((l & 7) * 16) ^ ((r & 7) << 4);
  gload16(Vp + (size_t)r * Sk + kt * 64 + cb / 2, Vsm + w * 1024);
}
__device__ __forceinline__ void kfrags(const uchar* Ksm, int l, short8 kf[8]) {
#pragma unroll
  for (int kc = 0; kc < 2; ++kc)
#pragma unroll
    for (int sub = 0; sub < 4; ++sub) {
      int row = sub * 16 + (l & 15);
      kf[kc * 4 + sub] = *(const short8*)(Ksm + SWZ(row, (kc * 32 + (l >> 4) * 8) * 2));
    }
}
// swapped QK^T: sfr[sub] = S^T; lane holds q=l&15, k = sub*16 + (l>>4)*4 + i
__device__ __forceinline__ void qk_swapped(const short8 qf[2], const short8 kf[8], f32x4 sfr[4]) {
  __builtin_amdgcn_s_setprio(1);
#pragma unroll
  for (int kc = 0; kc < 2; ++kc)
#pragma unroll
    for (int sub = 0; sub < 4; ++sub)
      sfr[sub] = __builtin_amdgcn_mfma_f32_16x16x32_bf16(kf[kc * 4 + sub], qf[kc], sfr[sub], 0, 0, 0);
  __builtin_amdgcn_s_setprio(0);
}
// V B-fragments in sigma-permuted k-order matching the in-register P layout
__device__ __forceinline__ void vfrags_sigma(const uchar* Vsm, int l, short8 vb[8]) {
#pragma unroll
  for (int kc = 0; kc < 2; ++kc)
#pragma unroll
    for (int ds = 0; ds < 4; ++ds) {
      int row = ds * 16 + (l & 15);
      union { s16x4 h[2]; short8 s; } u;
      u.h[0] = *(const s16x4*)(Vsm + SWZ(row, 64 * kc + 8 * (l >> 4)));
      u.h[1] = *(const s16x4*)(Vsm + SWZ(row, 64 * kc + 32 + 8 * (l >> 4)));
      vb[kc * 4 + ds] = u.s;
    }
}
// pack P (ps[sub*4+i], k=16sub+4hi+i) into sigma-ordered x32 A-frags
__device__ __forceinline__ void pa_sigma(const float ps[16], short8 pa[2]) {
#pragma unroll
  for (int kc = 0; kc < 2; ++kc) {
    union { unsigned u[4]; short8 s; } r;
    r.u[0] = cvtpk2(ps[8 * kc + 0], ps[8 * kc + 1]);
    r.u[1] = cvtpk2(ps[8 * kc + 2], ps[8 * kc + 3]);
    r.u[2] = cvtpk2(ps[8 * kc + 4], ps[8 * kc + 5]);
    r.u[3] = cvtpk2(ps[8 * kc + 6], ps[8 * kc + 7]);
    pa[kc] = r.s;
  }
}
__device__ __forceinline__ void pv_sigma(const short8 pa[2], const short8 vb[8], f32x4 og[4]) {
  __builtin_amdgcn_s_setprio(1);
#pragma unroll
  for (int kc = 0; kc < 2; ++kc)
#pragma unroll
    for (int ds = 0; ds < 4; ++ds)
      og[ds] = __builtin_amdgcn_mfma_f32_16x16x32_bf16(pa[kc], vb[kc * 4 + ds], og[ds], 0, 0, 0);
  __builtin_amdgcn_s_setprio(0);
}
// single dbuf sweep, counted-vmcnt barriers: og += exp2(S*C2)@V; ll = per-lane row-sum (q=l&15)
__device__ __forceinline__ void pass_unnorm(
    const u16* __restrict__ Kp, const u16* __restrict__ Vp, int Sk,
    const short8 qf[2], uchar* Ks0, uchar* Ks1, uchar* Vs0, uchar* Vs1,
    int w, int l, f32x4 og[4], float& ll)
{
  const int nkt = Sk >> 6;
  stage_k8(Kp, 0, Ks0, w, l);
  stage_v8(Vp, 0, Sk, Vs0, w, l);
  for (int kt = 0; kt < nkt; ++kt) {
    uchar* Kc = (kt & 1) ? Ks1 : Ks0;
    uchar* Vc = (kt & 1) ? Vs1 : Vs0;
    if (kt + 1 < nkt) {
      stage_k8(Kp, kt + 1, (kt & 1) ? Ks0 : Ks1, w, l);
      stage_v8(Vp, kt + 1, Sk, (kt & 1) ? Vs0 : Vs1, w, l);
      waitv2();                       // my stage(kt) landed; stage(kt+1) stays in flight
    } else {
      waitv0();
    }
    abar(); sbar();                   // all waves' stage(kt) visible
    short8 kf[8];
    kfrags(Kc, l, kf);
    f32x4 sfr[4] = {};
    qk_swapped(qf, kf, sfr);
    float ps[16];
#pragma unroll
    for (int sub = 0; sub < 4; ++sub)
#pragma unroll
      for (int i = 0; i < 4; ++i) {
        float p = exp2f(sfr[sub][i] * C2);
        ll += p;
        ps[sub * 4 + i] = p;
      }
    short8 pa[2];
    pa_sigma(ps, pa);
    short8 vb[8];
    vfrags_sigma(Vc, l, vb);
    pv_sigma(pa, vb, og);
    sbar(); abar();                   // buffer reads done before next overwrite
  }
}

// ============ merged dual-source attention, 512 thr (img ids 0..767, text 768..1151) ============
__global__ __launch_bounds__(512, 4) void attn_kernel(
    const u16* __restrict__ qi, const u16* __restrict__ ki, const u16* __restrict__ vti,
    const u16* __restrict__ qt, const u16* __restrict__ ktx, const u16* __restrict__ vtt,
    u16* __restrict__ cimg, u16* __restrict__ ctxt, float* __restrict__ weights)
{
  __shared__ uchar smem[32768];
  const int t = threadIdx.x, w = t >> 6, l = t & 63;
  uchar* Ks0 = smem;
  uchar* Ks1 = smem + 8192;
  uchar* Vs0 = smem + 16384;
  uchar* Vs1 = smem + 24576;

  const int bid = blockIdx.x;
  const int wk = (bid & 7) * 144 + (bid >> 3);     // bijective, 1152%8==0
  const bool img = wk < 768;
  const int id = img ? wk : wk - 768;
  const int x = img ? (id & 7) : (id & 3);
  const int head = img ? (id >> 3) : (id >> 2);    // b*12+h
  const int b = head / 12, h = head % 12;
  const int Sq = img ? 1024 : 512;
  const int SkA = img ? 1024 : 512, SkB = img ? 512 : 1024;
  const u16* Qp = (img ? qi : qt) + (size_t)head * Sq * 64;
  const u16* KpA = (img ? ki : ktx) + (size_t)head * SkA * 64;
  const u16* VpA = (img ? vti : vtt) + (size_t)head * 64 * SkA;
  const u16* KpB = (img ? ktx : ki) + (size_t)head * SkB * 64;
  const u16* VpB = (img ? vtt : vti) + (size_t)head * 64 * SkB;
  u16* CTX = img ? cimg : ctxt;
  float* PROBS = img ? weights : nullptr;
  const int q0 = x * 128;
  const int qrow = q0 + w * 16 + (l & 15);         // this lane's q row (within head)

  short8 qf[2];
  qf[0] = *(const short8*)(Qp + (size_t)qrow * 64 + (l >> 4) * 8);
  qf[1] = *(const short8*)(Qp + (size_t)qrow * 64 + 32 + (l >> 4) * 8);

  f32x4 of[4] = {};
  if (PROBS) {
    // ---- pass 1 over A: denominators only (K dbuf, counted vmcnt) ----
    float ll = 0.f;
    const int nkt = SkA >> 6;
    stage_k8(KpA, 0, Ks0, w, l);
    for (int kt = 0; kt < nkt; ++kt) {
      uchar* Kc = (kt & 1) ? Ks1 : Ks0;
      if (kt + 1 < nkt) {
        stage_k8(KpA, kt + 1, (kt & 1) ? Ks0 : Ks1, w, l);
        waitv1();
      } else {
        waitv0();
      }
      abar(); sbar();
      short8 kf[8];
      kfrags(Kc, l, kf);
      f32x4 sfr[4] = {};
      qk_swapped(qf, kf, sfr);
#pragma unroll
      for (int sub = 0; sub < 4; ++sub)
#pragma unroll
        for (int i = 0; i < 4; ++i) ll += exp2f(sfr[sub][i] * C2);
      sbar(); abar();
    }
    // pass-2 prologue staged early; reduce hides part of the latency
    stage_k8(KpA, 0, Ks0, w, l);
    stage_v8(VpA, 0, SkA, Vs0, w, l);
    ll += __shfl_xor(ll, 16);
    ll += __shfl_xor(ll, 32);
    const float lb = -__log2f(ll);                 // p_norm = exp2(S*C2 + lb)
    // ---- pass 2 over A: normalized probs direct-out + PV (K,V dbuf, counted vmcnt) ----
    float* prow = PROBS + ((size_t)head * Sq + qrow) * SkA;
    for (int kt = 0; kt < nkt; ++kt) {
      uchar* Kc = (kt & 1) ? Ks1 : Ks0;
      uchar* Vc = (kt & 1) ? Vs1 : Vs0;
      if (kt + 1 < nkt) {
        stage_k8(KpA, kt + 1, (kt & 1) ? Ks0 : Ks1, w, l);
        stage_v8(VpA, kt + 1, SkA, (kt & 1) ? Vs0 : Vs1, w, l);
        waitv2();
      } else {
        waitv0();
      }
      abar(); sbar();
      short8 kf[8];
      kfrags(Kc, l, kf);
      f32x4 sfr[4] = {};
      qk_swapped(qf, kf, sfr);
      float ps[16];
#pragma unroll
      for (int sub = 0; sub < 4; ++sub) {
#pragma unroll
        for (int i = 0; i < 4; ++i)
          ps[sub * 4 + i] = exp2f(sfr[sub][i] * C2 + lb);
        // direct probs store: row q=l&15, k = 16sub+4hi .. +3 (16B aligned)
        *(f32x4*)(prow + kt * 64 + sub * 16 + (l >> 4) * 4) = *(const f32x4*)&ps[sub * 4];
      }
      short8 pa[2];
      pa_sigma(ps, pa);
      short8 vb[8];
      vfrags_sigma(Vc, l, vb);
      pv_sigma(pa, vb, of);
      sbar(); abar();
    }
#pragma unroll
    for (int ds = 0; ds < 4; ++ds) of[ds] *= 0.5f;
  } else {
    float ll = 0.f;
    pass_unnorm(KpA, VpA, SkA, qf, Ks0, Ks1, Vs0, Vs1, w, l, of, ll);
    ll += __shfl_xor(ll, 16);
    ll += __shfl_xor(ll, 32);
    float r = 0.5f / ll;
#pragma unroll
    for (int i = 0; i < 4; ++i) {
      float lv = __int_as_float(__builtin_amdgcn_ds_bpermute(
          ((l >> 4) * 4 + i) * 4, __float_as_int(r)));
#pragma unroll
      for (int ds = 0; ds < 4; ++ds) of[ds][i] *= lv;
    }
  }
  // ---- source B: single unnormalized dbuf sweep ----
  {
    f32x4 og[4] = {};
    float l2 = 0.f;
    pass_unnorm(KpB, VpB, SkB, qf, Ks0, Ks1, Vs0, Vs1, w, l, og, l2);
    l2 += __shfl_xor(l2, 16);
    l2 += __shfl_xor(l2, 32);
    float r = 0.5f / l2;
#pragma unroll
    for (int i = 0; i < 4; ++i) {
      float lv = __int_as_float(__builtin_amdgcn_ds_bpermute(
          ((l >> 4) * 4 + i) * 4, __float_as_int(r)));
#pragma unroll
      for (int ds = 0; ds < 4; ++ds) of[ds][i] += og[ds][i] * lv;
    }
  }
  // ---- write merged ctx via per-wave LDS bounce (K/V buffers dead after barrier) ----
  __syncthreads();
  {
    uchar* Wb = smem + w * 2176;                   // 16 rows x 68 u16 (136B stride)
#pragma unroll
    for (int ds = 0; ds < 4; ++ds)
#pragma unroll
      for (int i = 0; i < 4; ++i)
        *(u16*)(Wb + ((l >> 4) * 4 + i) * 136 + (16 * ds + (l & 15)) * 2) = f2b(of[ds][i]);
#pragma unroll
    for (int i = 0; i < 2; ++i) {
      int it = i * 64 + l;
      int r = it >> 3, cg = it & 7;
      short8 v = *(const short8*)(Wb + r * 136 + cg * 16);
      int s = q0 + w * 16 + r;
      *(short8*)(CTX + ((size_t)b * Sq + s) * 768 + h * 64 + cg * 8) = v;
    }
  }
}

// ============ merged output projection (img ids 0..383, text 384..575) ============
__global__ __launch_bounds__(256) void outproj_kernel(
    const u16* __restrict__ cimg, const u16* __restrict__ ctxt,
    const u16* __restrict__ Wto, const float* __restrict__ bias,
    float* __restrict__ out_img, float* __restrict__ out_text)
{
  const int bid = blockIdx.x;
  const int wk = (bid & 7) * 72 + (bid >> 3);      // bijective, 576%8==0
  const bool img = wk < 384;
  const int id = img ? wk : wk - 384;
  const int y = img ? (id >> 6) : (id >> 5);       // same-y blocks share Wo panel
  const int x = img ? (id & 63) : (id & 31);
  const u16* C = img ? cimg : ctxt;
  float* OUT = img ? out_img : out_text;
  const int m0 = x * 128, n0 = y * 128;
  __shared__ unsigned char sm[32768];
  unsigned char* Asm = sm;
  unsigned char* Bsm = sm + 16384;
  const int t = threadIdx.x, w = t >> 6, l = t & 63;
  const int wm = (w & 1) * 64, wn = (w >> 1) * 64;
  f32x4 acc[4][4] = {};
  for (int k0 = 0; k0 < 768; k0 += 64) {
#pragma unroll
    for (int j = 0; j < 4; ++j) {
      int chunk = j * 4 + w;
      int r = chunk * 8 + (l >> 3);
      int cb = ((l & 7) * 16) ^ ((r & 7) << 4);
      gload16(C + (size_t)(m0 + r) * 768 + k0 + cb / 2, Asm + chunk * 1024);
    }
#pragma unroll
    for (int j = 0; j < 4; ++j) {
      int chunk = j * 4 + w;
      int r = chunk * 8 + (l >> 3);
      int cb = ((l & 7) * 16) ^ ((r & 7) << 4);
      gload16(Wto + (size_t)(n0 + r) * 768 + k0 + cb / 2, Bsm + chunk * 1024);
    }
    __syncthreads();
#pragma unroll
    for (int kc = 0; kc < 2; ++kc) {
      short8 af[4], bfr[4];
      const int koff = (kc * 32 + (l >> 4) * 8) * 2;
#pragma unroll
      for (int ms = 0; ms < 4; ++ms) {
        int row = wm + ms * 16 + (l & 15);
        af[ms] = *(const short8*)(Asm + SWZ(row, koff));
      }
#pragma unroll
      for (int ns = 0; ns < 4; ++ns) {
        int row = wn + ns * 16 + (l & 15);
        bfr[ns] = *(const short8*)(Bsm + SWZ(row, koff));
      }
      __builtin_amdgcn_s_setprio(1);
#pragma unroll
      for (int ms = 0; ms < 4; ++ms)
#pragma unroll
        for (int ns = 0; ns < 4; ++ns)
          acc[ms][ns] = __builtin_amdgcn_mfma_f32_16x16x32_bf16(af[ms], bfr[ns], acc[ms][ns], 0, 0, 0);
      __builtin_amdgcn_s_setprio(0);
    }
    __syncthreads();
  }
#pragma unroll
  for (int ms = 0; ms < 4; ++ms)
#pragma unroll
    for (int ns = 0; ns < 4; ++ns) {
      float bv = bias[n0 + wn + ns * 16 + (l & 15)];
#pragma unroll
      for (int i = 0; i < 4; ++i) {
        int mm = m0 + wm + ms * 16 + (l >> 4) * 4 + i;
        int nn = n0 + wn + ns * 16 + (l & 15);
        OUT[(size_t)mm * 768 + nn] = acc[ms][ns][i] + bv;
      }
    }
}

extern "C" void kernel_launch(void* const* d_in, const int* in_sizes, int n_in,
                              void* d_out, int out_size, void* d_ws, size_t ws_size,
                              hipStream_t stream)
{
  const float* hidden = (const float*)d_in[0];
  const float* text   = (const float*)d_in[1];
  const float* Wq  = (const float*)d_in[2];  const float* bq  = (const float*)d_in[3];
  const float* Wk  = (const float*)d_in[4];  const float* bk  = (const float*)d_in[5];
  const float* Wv  = (const float*)d_in[6];  const float* bv  = (const float*)d_in[7];
  const float* Wqt = (const float*)d_in[8];  const float* bqt = (const float*)d_in[9];
  const float* Wkt = (const float*)d_in[10]; const float* bkt = (const float*)d_in[11];
  const float* Wvt = (const float*)d_in[12]; const float* bvt = (const float*)d_in[13];
  const float* Wo  = (const float*)d_in[14]; const float* bo  = (const float*)d_in[15];

  u16* wt   = (u16*)d_ws;                 // 7 * 589824
  u16* xb   = wt + 7 * 589824;            // hidden bf16 (6291456) + text bf16 (3145728)
  u16* qi   = xb + 9437184;               // [8][12][1024][64]
  u16* ki   = qi + 6291456;
  u16* vti  = ki + 6291456;               // [8][12][64][1024]
  u16* qt   = vti + 6291456;              // [8][12][512][64]
  u16* ktx  = qt + 3145728;
  u16* vtt  = ktx + 3145728;              // [8][12][64][512]
  u16* cimg = vtt + 3145728;              // [8][1024][768] = 0.5*(ctx_ii+ctx_it)
  u16* ctxt = cimg + 6291456;             // [8][512][768]  = 0.5*(ctx_tt+ctx_ti)

  float* out_img  = (float*)d_out;
  float* out_text = out_img + 6291456;
  float* weights  = out_text + 3145728;

  prep_kernel<<<5616, 256, 0, stream>>>(Wq, Wk, Wv, Wqt, Wkt, Wvt, Wo, wt,
                                        hidden, text, xb);
  proj_kernel<<<1728, 256, 0, stream>>>(xb, wt, bq, bk, bv, bqt, bkt, bvt,
                                        qi, ki, vti, qt, ktx, vtt);
  attn_kernel<<<1152, 512, 0, stream>>>(qi, ki, vti, qt, ktx, vtt,
                                        cimg, ctxt, weights);
  outproj_kernel<<<576, 256, 0, stream>>>(cimg, ctxt, wt + 6 * 589824, bo,
                                          out_img, out_text);
}